// Round 1
// baseline (368.227 us; speedup 1.0000x reference)
//
#include <hip/hip_runtime.h>
#include <math.h>

#define BCOL 64
#define ED 512
#define NROWS 2048

// Pass A: per-wave online softmax over a chunk of rows of one column.
// Each wave (64 lanes) holds 8 row elements per lane (two float4 loads,
// fully coalesced: lanes cover [0,1KB) and [1KB,2KB) of the 2KB row).
__global__ void attn_partial_kernel(const float* __restrict__ emb,
                                    const float* __restrict__ W,
                                    float* __restrict__ accbuf,
                                    float* __restrict__ mbuf,
                                    float* __restrict__ lbuf,
                                    int G, int rowsPerWave)
{
    const int tid  = threadIdx.x;
    const int lane = tid & 63;
    const int wv   = tid >> 6;           // wave within block [0,4)
    const int blk  = blockIdx.x;
    const int col  = blk % BCOL;         // batch column b
    const int chunk = blk / BCOL;        // chunk of rows
    const int g = chunk * 4 + wv;        // partial id within column [0,G)
    const int n0 = g * rowsPerWave;

    // W_e = W[512:1024]; preload this wave's 8 weights per lane
    const float4* We4 = (const float4*)(W + 512);
    const float4 w0 = We4[lane];
    const float4 w1 = We4[lane + 64];

    float m = -INFINITY, l = 0.0f;
    float4 acc0 = {0.f, 0.f, 0.f, 0.f};
    float4 acc1 = {0.f, 0.f, 0.f, 0.f};

    // prefetch row n0
    const float4* row = (const float4*)(emb + ((size_t)n0 * BCOL + col) * ED);
    float4 a0 = row[lane];
    float4 a1 = row[lane + 64];

    for (int i = 0; i < rowsPerWave; ++i) {
        // prefetch next row before the dependent reduce/update chain
        float4 b0, b1;
        if (i + 1 < rowsPerWave) {
            const float4* nrow =
                (const float4*)(emb + ((size_t)(n0 + i + 1) * BCOL + col) * ED);
            b0 = nrow[lane];
            b1 = nrow[lane + 64];
        }
        // dot(emb_row, W_e): per-lane partial then 64-lane butterfly
        float p = a0.x * w0.x + a0.y * w0.y + a0.z * w0.z + a0.w * w0.w
                + a1.x * w1.x + a1.y * w1.y + a1.z * w1.z + a1.w * w1.w;
        #pragma unroll
        for (int off = 32; off > 0; off >>= 1)
            p += __shfl_xor(p, off, 64);
        const float s = p;   // logit (state_score cancels in softmax over n)

        const float mn   = fmaxf(m, s);
        const float corr = __expf(m - mn);   // exp(-inf)=0 on first iter
        const float pe   = __expf(s - mn);
        l = l * corr + pe;
        acc0.x = acc0.x * corr + pe * a0.x;
        acc0.y = acc0.y * corr + pe * a0.y;
        acc0.z = acc0.z * corr + pe * a0.z;
        acc0.w = acc0.w * corr + pe * a0.w;
        acc1.x = acc1.x * corr + pe * a1.x;
        acc1.y = acc1.y * corr + pe * a1.y;
        acc1.z = acc1.z * corr + pe * a1.z;
        acc1.w = acc1.w * corr + pe * a1.w;
        m = mn;

        a0 = b0;
        a1 = b1;
    }

    float4* out4 = (float4*)(accbuf + ((size_t)col * G + g) * ED);
    out4[lane]      = acc0;
    out4[lane + 64] = acc1;
    if (lane == 0) {
        mbuf[col * G + g] = m;
        lbuf[col * G + g] = l;
    }
}

// Pass B: combine G partials per column. grid = (BCOL * 2) blocks of 256
// threads; each block handles one (column, 256-element half) of the output.
__global__ void attn_reduce_kernel(const float* __restrict__ accbuf,
                                   const float* __restrict__ mbuf,
                                   const float* __restrict__ lbuf,
                                   float* __restrict__ out,
                                   int G)
{
    const int b    = blockIdx.x >> 1;
    const int half = blockIdx.x & 1;
    const int tid  = threadIdx.x;

    __shared__ float sc[64];
    if (tid < 64) {  // wave 0 computes the combine scales
        float mg = (tid < G) ? mbuf[b * G + tid] : -INFINITY;
        float lg = (tid < G) ? lbuf[b * G + tid] : 0.0f;
        float M = mg;
        #pragma unroll
        for (int off = 32; off > 0; off >>= 1)
            M = fmaxf(M, __shfl_xor(M, off, 64));
        float el = lg * __expf(mg - M);
        float L = el;
        #pragma unroll
        for (int off = 32; off > 0; off >>= 1)
            L += __shfl_xor(L, off, 64);
        sc[tid] = __expf(mg - M) / L;
    }
    __syncthreads();

    const int e = half * 256 + tid;
    float s = 0.0f;
    for (int gg = 0; gg < G; ++gg)
        s += sc[gg] * accbuf[((size_t)b * G + gg) * ED + e];
    out[(size_t)b * ED + e] = s;
}

extern "C" void kernel_launch(void* const* d_in, const int* in_sizes, int n_in,
                              void* d_out, int out_size, void* d_ws, size_t ws_size,
                              hipStream_t stream) {
    // inputs: 0=state_tm1 (unused: cancels in softmax), 1=embeddings,
    //         2=W (1024), 3=b (unused: cancels)
    const float* emb = (const float*)d_in[1];
    const float* W   = (const float*)d_in[2];
    float* out = (float*)d_out;

    // choose partials-per-column G to fit workspace (prefer 64 = 16 waves/CU)
    int G = 64;
    while (G > 4) {
        size_t need = (size_t)BCOL * G * ED * sizeof(float)
                    + 2 * (size_t)BCOL * G * sizeof(float);
        if (need <= ws_size) break;
        G >>= 1;
    }
    const int rowsPerWave = NROWS / G;

    float* accbuf = (float*)d_ws;
    float* mbuf = accbuf + (size_t)BCOL * G * ED;
    float* lbuf = mbuf + BCOL * G;

    attn_partial_kernel<<<dim3(BCOL * (G / 4)), dim3(256), 0, stream>>>(
        emb, W, accbuf, mbuf, lbuf, G, rowsPerWave);
    attn_reduce_kernel<<<dim3(BCOL * 2), dim3(256), 0, stream>>>(
        accbuf, mbuf, lbuf, out, G);
}